// Round 14
// baseline (166.485 us; speedup 1.0000x reference)
//
#include <hip/hip_runtime.h>

#define NEG 5
#define MM 6
#define NCTX 6
#define NC 36
#define DD 128
#define WPB 4           // waves per block
#define RPW 2
#define RPB (WPB * RPW)
#define DROW 12
#define S_SCALE 4096.0f
#define INV_S (1.0f / 4096.0f)

typedef float v2f __attribute__((ext_vector_type(2)));
typedef float v4f __attribute__((ext_vector_type(4)));

__device__ __forceinline__ int geti(const int4& v, int c) {
    switch (c) { case 0: return v.x; case 1: return v.y; case 2: return v.z; default: return v.w; }
}
__device__ __forceinline__ float getf(const float4& v, int c) {
    switch (c) { case 0: return v.x; case 1: return v.y; case 2: return v.z; default: return v.w; }
}

// ============ w-bag: wbuf[b] = sum_m emb0[w2m[b,m]] * mask ============
__global__ __launch_bounds__(256) void sg_w_kernel(
    const int*   __restrict__ w2m,
    const float* __restrict__ w2m_mask,
    const float* __restrict__ emb0,
    float*       __restrict__ wbuf,
    int B)
{
    const int lane  = threadIdx.x & 63;
    const int wid   = threadIdx.x >> 6;
    const int sub   = lane >> 5;
    const int slane = lane & 31;
    const int base  = lane & 32;
    const int b     = blockIdx.x * RPB + wid * RPW + sub;
    if (b >= B) return;

    int wi = 0; float wmk = 0.f;
    if (slane < MM)           wi  = w2m[(size_t)b * MM + slane];
    else if (slane < 2 * MM)  wmk = w2m_mask[(size_t)b * MM + (slane - MM)];

    const unsigned long long e0p = (unsigned long long)emb0;
    const unsigned int doff = (unsigned int)slane << 4;

    v4f rr[MM]; float mk[MM];
    #pragma unroll
    for (int m = 0; m < MM; ++m) {
        const int idx = __shfl(wi, base + m, 64);
        mk[m]         = __shfl(wmk, base + MM + m, 64);
        const unsigned int voff = ((unsigned int)idx << 9) + doff;
        asm volatile("global_load_dwordx4 %0, %1, %2"
                     : "=v"(rr[m]) : "v"(voff), "s"(e0p) : "memory");
    }
    asm volatile("s_waitcnt vmcnt(0)" ::: "memory");
    __builtin_amdgcn_sched_barrier(0);

    v4f acc = {0.f, 0.f, 0.f, 0.f};
    #pragma unroll
    for (int m = 0; m < MM; ++m) {
        acc[0] += rr[m][0] * mk[m]; acc[1] += rr[m][1] * mk[m];
        acc[2] += rr[m][2] * mk[m]; acc[3] += rr[m][3] * mk[m];
    }
    *reinterpret_cast<v4f*>(wbuf + (size_t)b * DD + slane * 4) = acc;
}

// ============ emb1 fp32 -> fp8(e4m3, x4096), nontemporal source ============
__global__ __launch_bounds__(256) void cvt_fp8_kernel(
    const float* __restrict__ emb1, unsigned int* __restrict__ q, long n4)
{
    const long stride = (long)gridDim.x * 256;
    for (long i = (long)blockIdx.x * 256 + threadIdx.x; i < n4; i += stride) {
        v4f v = __builtin_nontemporal_load(reinterpret_cast<const v4f*>(emb1) + i);
        int r = 0;
        r = __builtin_amdgcn_cvt_pk_fp8_f32(v[0] * S_SCALE, v[1] * S_SCALE, r, false);
        r = __builtin_amdgcn_cvt_pk_fp8_f32(v[2] * S_SCALE, v[3] * S_SCALE, r, true);
        q[i] = (unsigned int)r;
    }
}

// ============ dot kernel: ONE ROW PER WAVE, scalar indices/masks ============
__global__ __launch_bounds__(256) void sg_dot8s_kernel(
    const int*   __restrict__ data,
    const int*   __restrict__ c2m,        // [B,36]
    const float* __restrict__ c2m_mask,   // [B,36]
    const unsigned int* __restrict__ q,   // emb1 fp8, 128B/row
    const float* __restrict__ wbuf,       // [B,128]
    float*       __restrict__ out,
    int B)
{
    const int lane = threadIdx.x & 63;
    // wave-uniform row id -> index/mask reads become scalar s_loads
    const int wid  = __builtin_amdgcn_readfirstlane(threadIdx.x >> 6);
    const int b    = blockIdx.x * WPB + wid;

    float loss = 0.0f;
    if (b < B) {
        const int*   cp = c2m      + (size_t)b * NC;
        const float* mp = c2m_mask + (size_t)b * NC;

        // per-lane: dims 2*lane, 2*lane+1
        v2f w = *reinterpret_cast<const v2f*>(wbuf + (size_t)b * DD + lane * 2);
        w[0] *= INV_S; w[1] *= INV_S;

        const char* qb = (const char*)q + (unsigned int)lane * 2;

        float p[NCTX];
        #pragma unroll
        for (int j = 0; j < NCTX; ++j) {
            float pj = 0.f;
            #pragma unroll
            for (int m = 0; m < MM; ++m) {
                const int t = j * MM + m;
                const int   idx = cp[t];   // scalar (wave-uniform)
                const float mk  = mp[t];   // scalar
                const unsigned int u =
                    *reinterpret_cast<const unsigned short*>(qb + ((size_t)idx << 7));
                v2f lo = __builtin_amdgcn_cvt_pk_f32_fp8(u, false);
                pj += mk * (lo[0] * w[0] + lo[1] * w[1]);
            }
            p[j] = pj;
        }

        // full-wave butterfly reduce of the 6 dots
        #pragma unroll
        for (int j = 0; j < NCTX; ++j) {
            float v = p[j];
            #pragma unroll
            for (int off = 32; off >= 1; off >>= 1)
                v += __shfl_xor(v, off, 64);
            p[j] = v;
        }

        if (lane == 0) {
            float x = fminf(fmaxf(p[0], -10.0f), 10.0f);
            loss = log1pf(expf(-x));
            #pragma unroll
            for (int n = 0; n < NEG; ++n) {
                float y = fminf(fmaxf(-p[1 + n], -10.0f), 10.0f);
                float msk = (float)data[(size_t)b * DROW + 2 + NEG + n];
                loss += log1pf(expf(-y)) * msk;
            }
        }
    }

    __shared__ float sacc[WPB];
    if (lane == 0) sacc[wid] = loss;
    __syncthreads();
    if (threadIdx.x == 0) {
        float s = 0.0f;
        #pragma unroll
        for (int i = 0; i < WPB; ++i) s += sacc[i];
        atomicAdd(out, s);
    }
}

// ============ fallback: fused8 (emb0 fp32 inside) ============
__global__ __launch_bounds__(256) void sg_fused8_kernel(
    const int*   __restrict__ data,
    const int*   __restrict__ w2m,
    const float* __restrict__ w2m_mask,
    const int*   __restrict__ c2m,
    const float* __restrict__ c2m_mask,
    const float* __restrict__ emb0,
    const unsigned int* __restrict__ q,
    float*       __restrict__ out,
    int B)
{
    const int lane  = threadIdx.x & 63;
    const int wid   = threadIdx.x >> 6;
    const int sub   = lane >> 5;
    const int slane = lane & 31;
    const int base  = lane & 32;
    const int b     = blockIdx.x * RPB + wid * RPW + sub;

    float loss = 0.0f;
    if (b < B) {
        int4 ci = {0,0,0,0}; float4 cmk = {0.f,0.f,0.f,0.f};
        int wi = 0; float wmk = 0.f; int nm = 0;
        if (slane < 9)       ci  = reinterpret_cast<const int4*>(c2m + (size_t)b * NC)[slane];
        else if (slane < 18) cmk = reinterpret_cast<const float4*>(c2m_mask + (size_t)b * NC)[slane - 9];
        else if (slane < 24) wi  = w2m[(size_t)b * MM + (slane - 18)];
        else if (slane < 30) wmk = w2m_mask[(size_t)b * MM + (slane - 24)];
        if (slane < NEG) nm = data[(size_t)b * DROW + 2 + NEG + slane];

        float nmf[NEG];
        #pragma unroll
        for (int n = 0; n < NEG; ++n) nmf[n] = (float)__shfl(nm, base + n, 64);

        const int d0 = slane * 4;
        float4 wr[MM]; float wmks[MM];
        #pragma unroll
        for (int m = 0; m < MM; ++m) {
            const int idx = __shfl(wi, base + 18 + m, 64);
            wmks[m] = __shfl(wmk, base + 24 + m, 64);
            wr[m] = *reinterpret_cast<const float4*>(emb0 + (size_t)idx * DD + d0);
        }
        unsigned int rq[NC];
        #pragma unroll
        for (int t = 0; t < NC; ++t) {
            const int k = t >> 2, c = t & 3;
            const int idx = __shfl(geti(ci, c), base + k, 64);
            rq[t] = q[(size_t)idx * 32 + slane];
        }

        float4 w = {0.f,0.f,0.f,0.f};
        #pragma unroll
        for (int m = 0; m < MM; ++m) {
            w.x += wr[m].x * wmks[m]; w.y += wr[m].y * wmks[m];
            w.z += wr[m].z * wmks[m]; w.w += wr[m].w * wmks[m];
        }
        w.x *= INV_S; w.y *= INV_S; w.z *= INV_S; w.w *= INV_S;

        float p[NCTX];
        #pragma unroll
        for (int j = 0; j < NCTX; ++j) {
            float pj = 0.f;
            #pragma unroll
            for (int m = 0; m < MM; ++m) {
                const int t = j * MM + m;
                const int k = t >> 2, c = t & 3;
                const float mk = __shfl(getf(cmk, c), base + 9 + k, 64);
                v2f lo = __builtin_amdgcn_cvt_pk_f32_fp8(rq[t], false);
                v2f hi = __builtin_amdgcn_cvt_pk_f32_fp8(rq[t], true);
                pj += mk * (lo[0] * w.x + lo[1] * w.y + hi[0] * w.z + hi[1] * w.w);
            }
            p[j] = pj;
        }

        #pragma unroll
        for (int j = 0; j < NCTX; ++j) {
            float v = p[j];
            #pragma unroll
            for (int off = 16; off >= 1; off >>= 1) v += __shfl_xor(v, off, 64);
            p[j] = v;
        }
        if (slane == 0) {
            float x = fminf(fmaxf(p[0], -10.0f), 10.0f);
            loss = log1pf(expf(-x));
            #pragma unroll
            for (int n = 0; n < NEG; ++n) {
                float y = fminf(fmaxf(-p[1 + n], -10.0f), 10.0f);
                loss += log1pf(expf(-y)) * nmf[n];
            }
        }
    }
    __shared__ float sacc[RPB];
    if (slane == 0) sacc[wid * RPW + sub] = loss;
    __syncthreads();
    if (threadIdx.x == 0) {
        float s = 0.0f;
        #pragma unroll
        for (int i = 0; i < RPB; ++i) s += sacc[i];
        atomicAdd(out, s);
    }
}

extern "C" void kernel_launch(void* const* d_in, const int* in_sizes, int n_in,
                              void* d_out, int out_size, void* d_ws, size_t ws_size,
                              hipStream_t stream) {
    const int*   data     = (const int*)  d_in[0];
    const int*   w2m      = (const int*)  d_in[1];
    const float* w2m_mask = (const float*)d_in[2];
    const int*   c2m      = (const int*)  d_in[3];
    const float* c2m_mask = (const float*)d_in[4];
    const float* emb0     = (const float*)d_in[5];
    const float* emb1     = (const float*)d_in[6];
    float* out = (float*)d_out;

    const int B     = in_sizes[1] / MM;
    const int vocab = in_sizes[6] / DD;
    const int blocks = (B + RPB - 1) / RPB;

    (void)hipMemsetAsync(out, 0, sizeof(float), stream);

    const size_t qbytes = (size_t)vocab * DD;
    const size_t wbytes = (size_t)B * DD * sizeof(float);
    const long   n4     = (long)vocab * 32;

    if (ws_size >= qbytes + wbytes) {
        unsigned int* q = (unsigned int*)d_ws;
        float* wbuf = (float*)((char*)d_ws + qbytes);
        sg_w_kernel<<<blocks, 64 * WPB, 0, stream>>>(w2m, w2m_mask, emb0, wbuf, B);
        cvt_fp8_kernel<<<2048, 256, 0, stream>>>(emb1, q, n4);
        sg_dot8s_kernel<<<(B + WPB - 1) / WPB, 64 * WPB, 0, stream>>>(
            data, c2m, c2m_mask, q, wbuf, out, B);
    } else if (ws_size >= qbytes) {
        unsigned int* q = (unsigned int*)d_ws;
        cvt_fp8_kernel<<<2048, 256, 0, stream>>>(emb1, q, n4);
        sg_fused8_kernel<<<blocks, 64 * WPB, 0, stream>>>(
            data, w2m, w2m_mask, c2m, c2m_mask, emb0, q, out, B);
    }
}

// Round 15
// 158.409 us; speedup vs baseline: 1.0510x; 1.0510x over previous
//
#include <hip/hip_runtime.h>

#define NEG 5
#define MM 6
#define NCTX 6
#define NC 36
#define DD 128
#define WPB 4           // waves per block
#define RPW 2
#define RPB (WPB * RPW)
#define DROW 12
#define QS 4096.0f      // emb1 fp8 scale
#define WSC 256.0f      // w fp8 scale
#define INV_ALL (1.0f / (4096.0f * 256.0f))

typedef float v2f __attribute__((ext_vector_type(2)));
typedef float v4f __attribute__((ext_vector_type(4)));

__device__ __forceinline__ int geti(const int4& v, int c) {
    switch (c) { case 0: return v.x; case 1: return v.y; case 2: return v.z; default: return v.w; }
}
__device__ __forceinline__ float getf(const float4& v, int c) {
    switch (c) { case 0: return v.x; case 1: return v.y; case 2: return v.z; default: return v.w; }
}

// ============ w-bag -> fp8 wq[b]: 128B packed row, scale WSC ============
__global__ __launch_bounds__(256) void sg_w_kernel(
    const int*   __restrict__ w2m,
    const float* __restrict__ w2m_mask,
    const float* __restrict__ emb0,
    unsigned int* __restrict__ wq,        // [B,32] dwords (fp8 x4 each)
    int B)
{
    const int lane  = threadIdx.x & 63;
    const int wid   = threadIdx.x >> 6;
    const int sub   = lane >> 5;
    const int slane = lane & 31;
    const int base  = lane & 32;
    const int b     = blockIdx.x * RPB + wid * RPW + sub;
    if (b >= B) return;

    int wi = 0; float wmk = 0.f;
    if (slane < MM)           wi  = w2m[(size_t)b * MM + slane];
    else if (slane < 2 * MM)  wmk = w2m_mask[(size_t)b * MM + (slane - MM)];

    const unsigned long long e0p = (unsigned long long)emb0;
    const unsigned int doff = (unsigned int)slane << 4;

    v4f rr[MM]; float mk[MM];
    #pragma unroll
    for (int m = 0; m < MM; ++m) {
        const int idx = __shfl(wi, base + m, 64);
        mk[m]         = __shfl(wmk, base + MM + m, 64);
        const unsigned int voff = ((unsigned int)idx << 9) + doff;
        asm volatile("global_load_dwordx4 %0, %1, %2"
                     : "=v"(rr[m]) : "v"(voff), "s"(e0p) : "memory");
    }
    asm volatile("s_waitcnt vmcnt(0)" ::: "memory");
    __builtin_amdgcn_sched_barrier(0);

    v4f acc = {0.f, 0.f, 0.f, 0.f};
    #pragma unroll
    for (int m = 0; m < MM; ++m) {
        acc[0] += rr[m][0] * mk[m]; acc[1] += rr[m][1] * mk[m];
        acc[2] += rr[m][2] * mk[m]; acc[3] += rr[m][3] * mk[m];
    }
    int r = 0;
    r = __builtin_amdgcn_cvt_pk_fp8_f32(acc[0] * WSC, acc[1] * WSC, r, false);
    r = __builtin_amdgcn_cvt_pk_fp8_f32(acc[2] * WSC, acc[3] * WSC, r, true);
    wq[(size_t)b * 32 + slane] = (unsigned int)r;
}

// ============ emb1 fp32 -> fp8(e4m3, xQS), nontemporal source ============
__global__ __launch_bounds__(256) void cvt_fp8_kernel(
    const float* __restrict__ emb1, unsigned int* __restrict__ q, long n4)
{
    const long stride = (long)gridDim.x * 256;
    for (long i = (long)blockIdx.x * 256 + threadIdx.x; i < n4; i += stride) {
        v4f v = __builtin_nontemporal_load(reinterpret_cast<const v4f*>(emb1) + i);
        int r = 0;
        r = __builtin_amdgcn_cvt_pk_fp8_f32(v[0] * QS, v[1] * QS, r, false);
        r = __builtin_amdgcn_cvt_pk_fp8_f32(v[2] * QS, v[3] * QS, r, true);
        q[i] = (unsigned int)r;
    }
}

// ============ dot: lane = (context, morpheme); NO index shuffles ============
__global__ __launch_bounds__(256) void sg_dotm_kernel(
    const int*   __restrict__ data,       // [B,12]
    const int*   __restrict__ c2m,        // [B,36]
    const float* __restrict__ c2m_mask,   // [B,36]
    const unsigned int* __restrict__ q,   // emb1 fp8, 32 dwords/row
    const unsigned int* __restrict__ wq,  // w fp8,    32 dwords/row
    float*       __restrict__ out,
    int B)
{
    const int lane = threadIdx.x & 63;
    const int wid  = __builtin_amdgcn_readfirstlane(threadIdx.x >> 6);
    const int b    = blockIdx.x * WPB + wid;     // one row per wave

    float term = 0.0f;
    if (b < B) {
        const int j = lane >> 3;          // context 0..7 (6..7 inactive)
        const int m = lane & 7;           // morpheme 0..7 (6..7 inactive)
        const bool act = (j < NCTX) && (m < MM);
        const int t = act ? (j * MM + m) : 0;

        // per-lane index + mask (coalesced loads, zero distribution cost)
        const int   idx = c2m[(size_t)b * NC + t];
        const float mk  = act ? c2m_mask[(size_t)b * NC + t] * INV_ALL : 0.f;

        // w row: wave-uniform -> s_load into SGPRs (32 dwords = 128 fp8 dims)
        const uint4* wrow = reinterpret_cast<const uint4*>(wq + (size_t)b * 32);
        uint4 wreg[8];
        #pragma unroll
        for (int c = 0; c < 8; ++c) wreg[c] = wrow[c];

        // gather this lane's morpheme row: 8 x dwordx4 (inst0 fills L1, rest hit)
        const uint4* qrow = reinterpret_cast<const uint4*>(
            (const char*)q + ((size_t)(unsigned int)idx << 7));
        uint4 qreg[8];
        #pragma unroll
        for (int c = 0; c < 8; ++c) qreg[c] = qrow[c];

        // full 128-dim dot in-lane
        v2f acc = {0.f, 0.f};
        #pragma unroll
        for (int c = 0; c < 8; ++c) {
            const unsigned int qd[4] = {qreg[c].x, qreg[c].y, qreg[c].z, qreg[c].w};
            const unsigned int wd[4] = {wreg[c].x, wreg[c].y, wreg[c].z, wreg[c].w};
            #pragma unroll
            for (int k = 0; k < 4; ++k) {
                v2f ql = __builtin_amdgcn_cvt_pk_f32_fp8(qd[k], false);
                v2f qh = __builtin_amdgcn_cvt_pk_f32_fp8(qd[k], true);
                v2f wl = __builtin_amdgcn_cvt_pk_f32_fp8(wd[k], false);
                v2f wh = __builtin_amdgcn_cvt_pk_f32_fp8(wd[k], true);
                acc += ql * wl;
                acc += qh * wh;
            }
        }
        float pm = (acc[0] + acc[1]) * mk;   // masked morpheme contribution

        // sum 6 morphemes within the 8-lane group (3 ds ops)
        pm += __shfl_xor(pm, 1, 64);
        pm += __shfl_xor(pm, 2, 64);
        pm += __shfl_xor(pm, 4, 64);         // every lane of group has p_j

        // leaders (m==0, j<6) compute their loss term
        if (m == 0 && j < NCTX) {
            if (j == 0) {
                float x = fminf(fmaxf(pm, -10.0f), 10.0f);
                term = log1pf(expf(-x));
            } else {
                float y = fminf(fmaxf(-pm, -10.0f), 10.0f);
                float msk = (float)data[(size_t)b * DROW + 2 + NEG + (j - 1)];
                term = log1pf(expf(-y)) * msk;
            }
        }
        // sum the 6 leader terms (lanes 0,8,..,40; 48/56 contribute 0)
        term += __shfl_xor(term, 8, 64);
        term += __shfl_xor(term, 16, 64);
        term += __shfl_xor(term, 32, 64);    // lane 0 holds row loss
    }

    __shared__ float sacc[WPB];
    if (lane == 0) sacc[wid] = term;
    __syncthreads();
    if (threadIdx.x == 0) {
        float s = 0.0f;
        #pragma unroll
        for (int i = 0; i < WPB; ++i) s += sacc[i];
        atomicAdd(out, s);
    }
}

// ============ fallback: fused8 (emb0 fp32 inside, q fp8) ============
__global__ __launch_bounds__(256) void sg_fused8_kernel(
    const int*   __restrict__ data,
    const int*   __restrict__ w2m,
    const float* __restrict__ w2m_mask,
    const int*   __restrict__ c2m,
    const float* __restrict__ c2m_mask,
    const float* __restrict__ emb0,
    const unsigned int* __restrict__ q,
    float*       __restrict__ out,
    int B)
{
    const int lane  = threadIdx.x & 63;
    const int wid   = threadIdx.x >> 6;
    const int sub   = lane >> 5;
    const int slane = lane & 31;
    const int base  = lane & 32;
    const int b     = blockIdx.x * RPB + wid * RPW + sub;

    float loss = 0.0f;
    if (b < B) {
        int4 ci = {0,0,0,0}; float4 cmk = {0.f,0.f,0.f,0.f};
        int wi = 0; float wmk = 0.f; int nm = 0;
        if (slane < 9)       ci  = reinterpret_cast<const int4*>(c2m + (size_t)b * NC)[slane];
        else if (slane < 18) cmk = reinterpret_cast<const float4*>(c2m_mask + (size_t)b * NC)[slane - 9];
        else if (slane < 24) wi  = w2m[(size_t)b * MM + (slane - 18)];
        else if (slane < 30) wmk = w2m_mask[(size_t)b * MM + (slane - 24)];
        if (slane < NEG) nm = data[(size_t)b * DROW + 2 + NEG + slane];

        float nmf[NEG];
        #pragma unroll
        for (int n = 0; n < NEG; ++n) nmf[n] = (float)__shfl(nm, base + n, 64);

        const int d0 = slane * 4;
        float4 wr[MM]; float wmks[MM];
        #pragma unroll
        for (int m = 0; m < MM; ++m) {
            const int idx = __shfl(wi, base + 18 + m, 64);
            wmks[m] = __shfl(wmk, base + 24 + m, 64);
            wr[m] = *reinterpret_cast<const float4*>(emb0 + (size_t)idx * DD + d0);
        }
        unsigned int rq[NC];
        #pragma unroll
        for (int t = 0; t < NC; ++t) {
            const int k = t >> 2, c = t & 3;
            const int idx = __shfl(geti(ci, c), base + k, 64);
            rq[t] = q[(size_t)idx * 32 + slane];
        }

        float4 w = {0.f,0.f,0.f,0.f};
        #pragma unroll
        for (int m = 0; m < MM; ++m) {
            w.x += wr[m].x * wmks[m]; w.y += wr[m].y * wmks[m];
            w.z += wr[m].z * wmks[m]; w.w += wr[m].w * wmks[m];
        }
        const float invq = 1.0f / QS;
        w.x *= invq; w.y *= invq; w.z *= invq; w.w *= invq;

        float p[NCTX];
        #pragma unroll
        for (int j = 0; j < NCTX; ++j) {
            float pj = 0.f;
            #pragma unroll
            for (int m = 0; m < MM; ++m) {
                const int t = j * MM + m;
                const int k = t >> 2, c = t & 3;
                const float mk = __shfl(getf(cmk, c), base + 9 + k, 64);
                v2f lo = __builtin_amdgcn_cvt_pk_f32_fp8(rq[t], false);
                v2f hi = __builtin_amdgcn_cvt_pk_f32_fp8(rq[t], true);
                pj += mk * (lo[0] * w.x + lo[1] * w.y + hi[0] * w.z + hi[1] * w.w);
            }
            p[j] = pj;
        }

        #pragma unroll
        for (int j = 0; j < NCTX; ++j) {
            float v = p[j];
            #pragma unroll
            for (int off = 16; off >= 1; off >>= 1) v += __shfl_xor(v, off, 64);
            p[j] = v;
        }
        if (slane == 0) {
            float x = fminf(fmaxf(p[0], -10.0f), 10.0f);
            loss = log1pf(expf(-x));
            #pragma unroll
            for (int n = 0; n < NEG; ++n) {
                float y = fminf(fmaxf(-p[1 + n], -10.0f), 10.0f);
                loss += log1pf(expf(-y)) * nmf[n];
            }
        }
    }
    __shared__ float sacc[RPB];
    if (slane == 0) sacc[wid * RPW + sub] = loss;
    __syncthreads();
    if (threadIdx.x == 0) {
        float s = 0.0f;
        #pragma unroll
        for (int i = 0; i < RPB; ++i) s += sacc[i];
        atomicAdd(out, s);
    }
}

extern "C" void kernel_launch(void* const* d_in, const int* in_sizes, int n_in,
                              void* d_out, int out_size, void* d_ws, size_t ws_size,
                              hipStream_t stream) {
    const int*   data     = (const int*)  d_in[0];
    const int*   w2m      = (const int*)  d_in[1];
    const float* w2m_mask = (const float*)d_in[2];
    const int*   c2m      = (const int*)  d_in[3];
    const float* c2m_mask = (const float*)d_in[4];
    const float* emb0     = (const float*)d_in[5];
    const float* emb1     = (const float*)d_in[6];
    float* out = (float*)d_out;

    const int B     = in_sizes[1] / MM;
    const int vocab = in_sizes[6] / DD;
    const int blocks = (B + RPB - 1) / RPB;

    (void)hipMemsetAsync(out, 0, sizeof(float), stream);

    const size_t qbytes  = (size_t)vocab * DD;    // fp8 emb1 table
    const size_t wqbytes = (size_t)B * DD;        // fp8 w table
    const long   n4      = (long)vocab * 32;

    if (ws_size >= qbytes + wqbytes) {
        unsigned int* q  = (unsigned int*)d_ws;
        unsigned int* wq = (unsigned int*)((char*)d_ws + qbytes);
        sg_w_kernel<<<blocks, 64 * WPB, 0, stream>>>(w2m, w2m_mask, emb0, wq, B);
        cvt_fp8_kernel<<<2048, 256, 0, stream>>>(emb1, q, n4);
        sg_dotm_kernel<<<(B + WPB - 1) / WPB, 64 * WPB, 0, stream>>>(
            data, c2m, c2m_mask, q, wq, out, B);
    } else if (ws_size >= qbytes) {
        unsigned int* q = (unsigned int*)d_ws;
        cvt_fp8_kernel<<<2048, 256, 0, stream>>>(emb1, q, n4);
        sg_fused8_kernel<<<blocks, 64 * WPB, 0, stream>>>(
            data, w2m, w2m_mask, c2m, c2m_mask, emb0, q, out, B);
    }
}

// Round 16
// 96.779 us; speedup vs baseline: 1.7203x; 1.6368x over previous
//
#include <hip/hip_runtime.h>

#define NEG 5
#define MM 6
#define NCTX 6
#define NC 36
#define DD 128
#define WPB 4
#define RPW 2
#define RPB (WPB * RPW)
#define DROW 12
#define QS 4096.0f
#define INV_S (1.0f / 4096.0f)

#define SB() __builtin_amdgcn_sched_barrier(0)

typedef float v2f __attribute__((ext_vector_type(2)));
typedef float v4f __attribute__((ext_vector_type(4)));

__device__ __forceinline__ int geti(const int4& v, int c) {
    switch (c) { case 0: return v.x; case 1: return v.y; case 2: return v.z; default: return v.w; }
}
__device__ __forceinline__ float getf(const float4& v, int c) {
    switch (c) { case 0: return v.x; case 1: return v.y; case 2: return v.z; default: return v.w; }
}

// ============ emb1 fp32 -> fp8(e4m3, xQS); 2x dwordx4 per iter ============
__global__ __launch_bounds__(256) void cvt_fp8_kernel(
    const float* __restrict__ emb1, unsigned int* __restrict__ q, long n4)
{
    const long stride = (long)gridDim.x * 512;
    for (long i0 = (long)blockIdx.x * 512 + threadIdx.x; i0 < n4; i0 += stride) {
        const long i1 = i0 + 256;
        v4f a = __builtin_nontemporal_load(reinterpret_cast<const v4f*>(emb1) + i0);
        int ra = 0;
        ra = __builtin_amdgcn_cvt_pk_fp8_f32(a[0] * QS, a[1] * QS, ra, false);
        ra = __builtin_amdgcn_cvt_pk_fp8_f32(a[2] * QS, a[3] * QS, ra, true);
        q[i0] = (unsigned int)ra;
        if (i1 < n4) {
            v4f b = __builtin_nontemporal_load(reinterpret_cast<const v4f*>(emb1) + i1);
            int rb = 0;
            rb = __builtin_amdgcn_cvt_pk_fp8_f32(b[0] * QS, b[1] * QS, rb, false);
            rb = __builtin_amdgcn_cvt_pk_fp8_f32(b[2] * QS, b[3] * QS, rb, true);
            q[i1] = (unsigned int)rb;
        }
    }
}

// ============ fused: w-bag(emb0 fp32) + fp8 ctx dots, grid-stride ============
__global__ __launch_bounds__(256, 8) void sg_fused8_kernel(
    const int*   __restrict__ data,
    const int*   __restrict__ w2m,
    const float* __restrict__ w2m_mask,
    const int*   __restrict__ c2m,
    const float* __restrict__ c2m_mask,
    const float* __restrict__ emb0,
    const unsigned int* __restrict__ q,
    float*       __restrict__ out,
    int B, int nblk)
{
    const int lane  = threadIdx.x & 63;
    const int wid   = threadIdx.x >> 6;
    const int sub   = lane >> 5;
    const int slane = lane & 31;
    const int base  = lane & 32;

    float blk_loss = 0.0f;

    for (int blk = blockIdx.x; blk < nblk; blk += gridDim.x) {
        const int b = blk * RPB + wid * RPW + sub;
        float loss = 0.0f;
        if (b < B) {
            int4 ci = {0,0,0,0}; float4 cmk = {0.f,0.f,0.f,0.f};
            int wi = 0; float wmk = 0.f; int nm = 0;
            if (slane < 9)       ci  = reinterpret_cast<const int4*>(c2m + (size_t)b * NC)[slane];
            else if (slane < 18) cmk = reinterpret_cast<const float4*>(c2m_mask + (size_t)b * NC)[slane - 9];
            else if (slane < 24) wi  = w2m[(size_t)b * MM + (slane - 18)];
            else if (slane < 30) wmk = w2m_mask[(size_t)b * MM + (slane - 24)];
            if (slane < NEG) nm = data[(size_t)b * DROW + 2 + NEG + slane];

            float nmf[NEG];
            #pragma unroll
            for (int n = 0; n < NEG; ++n) nmf[n] = (float)__shfl(nm, base + n, 64);

            const int d0 = slane * 4;
            float4 wr[MM]; float wmks[MM];
            #pragma unroll
            for (int m = 0; m < MM; ++m) {
                const int idx = __shfl(wi, base + 18 + m, 64);
                wmks[m] = __shfl(wmk, base + 24 + m, 64);
                // unsigned 32-bit element offset -> saddr-form load
                const unsigned int eo = (unsigned int)idx * (unsigned int)DD + (unsigned int)d0;
                wr[m] = *reinterpret_cast<const float4*>(emb0 + eo);
            }
            unsigned int rq[NC];
            #pragma unroll
            for (int t = 0; t < NC; ++t) {
                const int k = t >> 2, c = t & 3;
                const int idx = __shfl(geti(ci, c), base + k, 64);
                const unsigned int eo = (unsigned int)idx * 32u + (unsigned int)slane;
                rq[t] = q[eo];
            }

            float4 w = {0.f,0.f,0.f,0.f};
            #pragma unroll
            for (int m = 0; m < MM; ++m) {
                w.x += wr[m].x * wmks[m]; w.y += wr[m].y * wmks[m];
                w.z += wr[m].z * wmks[m]; w.w += wr[m].w * wmks[m];
            }
            w.x *= INV_S; w.y *= INV_S; w.z *= INV_S; w.w *= INV_S;

            float p[NCTX];
            #pragma unroll
            for (int j = 0; j < NCTX; ++j) {
                float pj = 0.f;
                #pragma unroll
                for (int m = 0; m < MM; ++m) {
                    const int t = j * MM + m;
                    const int k = t >> 2, c = t & 3;
                    const float mk = __shfl(getf(cmk, c), base + 9 + k, 64);
                    v2f lo = __builtin_amdgcn_cvt_pk_f32_fp8(rq[t], false);
                    v2f hi = __builtin_amdgcn_cvt_pk_f32_fp8(rq[t], true);
                    pj += mk * (lo[0] * w.x + lo[1] * w.y + hi[0] * w.z + hi[1] * w.w);
                }
                p[j] = pj;
            }

            #pragma unroll
            for (int j = 0; j < NCTX; ++j) {
                float v = p[j];
                #pragma unroll
                for (int off = 16; off >= 1; off >>= 1) v += __shfl_xor(v, off, 64);
                p[j] = v;
            }
            if (slane == 0) {
                float x = fminf(fmaxf(p[0], -10.0f), 10.0f);
                loss = log1pf(expf(-x));
                #pragma unroll
                for (int n = 0; n < NEG; ++n) {
                    float y = fminf(fmaxf(-p[1 + n], -10.0f), 10.0f);
                    loss += log1pf(expf(-y)) * nmf[n];
                }
            }
        }
        blk_loss += loss;
    }

    // one atomic per block for the whole grid-stride accumulation
    __shared__ float sacc[RPB];
    if (slane == 0) sacc[wid * RPW + sub] = blk_loss;
    __syncthreads();
    if (threadIdx.x == 0) {
        float s = 0.0f;
        #pragma unroll
        for (int i = 0; i < RPB; ++i) s += sacc[i];
        atomicAdd(out, s);
    }
}

extern "C" void kernel_launch(void* const* d_in, const int* in_sizes, int n_in,
                              void* d_out, int out_size, void* d_ws, size_t ws_size,
                              hipStream_t stream) {
    const int*   data     = (const int*)  d_in[0];
    const int*   w2m      = (const int*)  d_in[1];
    const float* w2m_mask = (const float*)d_in[2];
    const int*   c2m      = (const int*)  d_in[3];
    const float* c2m_mask = (const float*)d_in[4];
    const float* emb0     = (const float*)d_in[5];
    const float* emb1     = (const float*)d_in[6];
    float* out = (float*)d_out;

    const int B     = in_sizes[1] / MM;
    const int vocab = in_sizes[6] / DD;
    const int nblk  = (B + RPB - 1) / RPB;        // logical row-blocks
    const long n4   = (long)vocab * 32;

    (void)hipMemsetAsync(out, 0, sizeof(float), stream);

    unsigned int* q = (unsigned int*)d_ws;        // fp8 table, vocab*128 B
    cvt_fp8_kernel<<<4096, 256, 0, stream>>>(emb1, q, n4);

    const int grid = (nblk < 2048) ? nblk : 2048; // persistent blocks, 8/CU
    sg_fused8_kernel<<<grid, 64 * WPB, 0, stream>>>(
        data, w2m, w2m_mask, c2m, c2m_mask, emb0, q, out, B, nblk);
}